// Round 13
// baseline (181.107 us; speedup 1.0000x reference)
//
#include <hip/hip_runtime.h>
#include <hip/hip_bf16.h>

#define N_NODES 100000
#define N_EDGES 6500000
#define IN_FEATS 16
#define HIDDEN 8
#define N_CLASSES 2
#define BK 196            // nodes per bucket
#define NBK 512           // buckets: 512*196 = 100352 >= 100000
#define EPB 8192          // edges per block in binfill
#define CAP 16384         // fixed slots per bucket (max true load ~13.3K)

// Monotone float -> uint key (order-preserving); 0 is below every real key.
__device__ __forceinline__ unsigned f2key(float f) {
    int i = __float_as_int(f);
    return (unsigned)(i ^ ((i >> 31) | 0x80000000));
}
__device__ __forceinline__ float key2f(unsigned u) {
    int i = (u & 0x80000000u) ? (int)(u ^ 0x80000000u) : (int)(~u);
    return __int_as_float(i);
}
__device__ __forceinline__ unsigned bf16_1(float f0) {
    unsigned u0 = __float_as_uint(f0);
    return (u0 + 0x7FFFu + ((u0 >> 16) & 1u)) >> 16;   // RNE
}
__device__ __forceinline__ unsigned pack_bf16(float f0, float f1) {
    return bf16_1(f0) | (bf16_1(f1) << 16);
}

// ---------- cursor init: cursor[b] = b*CAP ----------
__global__ void init_cursor(unsigned* __restrict__ cursor) {
    int t = threadIdx.x;
    if (t < NBK) cursor[t] = (unsigned)t * CAP;
}

// ---------- bin-fill + fused x->bf16 convert (6-byte split records) ----------
__global__ __launch_bounds__(1024, 8) void binfill(
    const float* __restrict__ x, const int* __restrict__ src,
    const int* __restrict__ dst, const float* __restrict__ ts,
    unsigned* __restrict__ cursor, unsigned* __restrict__ binnedM,
    unsigned short* __restrict__ binnedT, unsigned* __restrict__ xb) {
    __shared__ uint2 stage[EPB];          // 64 KB, bucket-sorted records
    __shared__ unsigned lcnt[NBK];
    __shared__ unsigned lstart[NBK + 1];
    __shared__ unsigned shiftv[NBK];      // global_base - local_start
    __shared__ unsigned chunkb[EPB / 64]; // bucket of each 64-record chunk
    __shared__ unsigned waveTot[8], waveBase[8];
    int t = threadIdx.x;
    if (t < NBK) lcnt[t] = 0u;
    // phase 0: x -> bf16 table (grid-strided; complete before layer1 kernel)
    for (int i = blockIdx.x * 1024 + t; i < N_NODES * IN_FEATS / 2; i += gridDim.x * 1024)
        xb[i] = pack_bf16(x[2 * i], x[2 * i + 1]);
    __syncthreads();
    int base = blockIdx.x * EPB;
    // phase 1a: preload 8 dst values (independent loads in flight)
    unsigned dvals[8];
#pragma unroll
    for (int k = 0; k < 8; ++k) {
        int e = base + k * 1024 + t;
        dvals[k] = (e < N_EDGES) ? (unsigned)__builtin_nontemporal_load(&dst[e]) : 0xFFFFFFFFu;
    }
    // phase 1b: count + capture slot
    unsigned pk[8];                       // drow<<22 | b<<13 | slot
#pragma unroll
    for (int k = 0; k < 8; ++k) {
        pk[k] = 0xFFFFFFFFu;
        if (dvals[k] != 0xFFFFFFFFu) {
            unsigned d = dvals[k];
            unsigned b = d / BK;
            unsigned slot = atomicAdd(&lcnt[b], 1u);
            pk[k] = ((d - b * BK) << 22) | (b << 13) | slot;
        }
    }
    __syncthreads();
    // phase 2: wave-shfl scan over lcnt -> lstart; reserve global runs
    unsigned c = (t < NBK) ? lcnt[t] : 0u;
    unsigned inc = c;
    int lane = t & 63;
#pragma unroll
    for (int d = 1; d < 64; d <<= 1) {
        unsigned v = __shfl_up(inc, d, 64);
        if (lane >= d) inc += v;
    }
    if (t < NBK && lane == 63) waveTot[t >> 6] = inc;
    __syncthreads();
    if (t == 0) {
        unsigned acc = 0;
#pragma unroll
        for (int w = 0; w < 8; ++w) { waveBase[w] = acc; acc += waveTot[w]; }
    }
    __syncthreads();
    if (t < NBK) {
        unsigned excl = waveBase[t >> 6] + inc - c;
        lstart[t] = excl;
        unsigned gb = atomicAdd(&cursor[t], c);   // block-private run in [b*CAP ...)
        shiftv[t] = gb - excl;
        if (t == NBK - 1) lstart[NBK] = excl + c;
    }
    __syncthreads();
    // phase 3: reload src/ts (L2-hot), scatter into stage (bucket-sorted)
#pragma unroll
    for (int k = 0; k < 8; ++k) {
        if (pk[k] != 0xFFFFFFFFu) {
            int e = base + k * 1024 + t;
            unsigned b = (pk[k] >> 13) & 511u;
            unsigned pos = lstart[b] + (pk[k] & 8191u);
            unsigned sv = (unsigned)__builtin_nontemporal_load(&src[e]);
            float tv = __builtin_nontemporal_load(&ts[e]);
            stage[pos] = make_uint2(sv | ((pk[k] >> 22) << 17), __float_as_uint(tv));
        }
    }
    __syncthreads();
    unsigned total = lstart[NBK];
    // phase 4a: chunk->bucket table (one binary search per 64 records)
    if (t < EPB / 64) {
        unsigned i = (unsigned)t * 64u;
        if (i < total) {
            unsigned lo = 0, hi = NBK - 1;
            while (lo < hi) {
                unsigned mid = (lo + hi + 1) >> 1;
                if (lstart[mid] <= i) lo = mid; else hi = mid - 1;
            }
            chunkb[t] = lo;
        }
    }
    __syncthreads();
    // phase 4b: dense copy-out; chunk-seeded walk, coalesced nt stores (6B)
#pragma unroll
    for (int j = 0; j < 8; ++j) {
        unsigned i = (unsigned)t + j * 1024u;
        if (i < total) {
            unsigned lo = chunkb[i >> 6];
            while (i >= lstart[lo + 1]) ++lo;
            uint2 v = stage[i];
            unsigned pos = i + shiftv[lo];
            __builtin_nontemporal_store(v.x, &binnedM[pos]);
            __builtin_nontemporal_store((unsigned short)bf16_1(__uint_as_float(v.y)),
                                        &binnedT[pos]);
        }
    }
}

// ---------- 16-feat compare-then-atomic from packed-bf16 pair of uint4 ----------
__device__ __forceinline__ void agg16c(unsigned* row, uint4 a, uint4 b, float tv) {
    const unsigned* pa = (const unsigned*)&a;
    const unsigned* pb = (const unsigned*)&b;
#pragma unroll
    for (int w = 0; w < 8; ++w) {
        unsigned u = (w < 4) ? pa[w] : pb[w - 4];
        unsigned k0 = f2key(__uint_as_float(u << 16) * tv);
        unsigned k1 = f2key(__uint_as_float(u & 0xFFFF0000u) * tv);
        uint2 cur = *(const uint2*)(row + 2 * w);
        if (k0 > cur.x) atomicMax(row + 2 * w,     k0);
        if (k1 > cur.y) atomicMax(row + 2 * w + 1, k1);
    }
}

// ---------- fused layer 1: bf16 gather + LDS max + GEMV 16->8 + relu ----------
__global__ __launch_bounds__(1024, 8) void layer1(
    const unsigned* __restrict__ cursor, const unsigned* __restrict__ binnedM,
    const unsigned short* __restrict__ binnedT, const uint4* __restrict__ xb,
    const float* __restrict__ W1, const float* __restrict__ b1,
    uint4* __restrict__ hb) {
    __shared__ uint2 tile2[BK * 9];       // stride 18 u32 per node row
    __shared__ float sW[IN_FEATS * HIDDEN];
    __shared__ float sb[HIDDEN];
    unsigned* tile = (unsigned*)tile2;
    int t = threadIdx.x;
    if (t < IN_FEATS * HIDDEN) sW[t] = W1[t];
    if (t < HIDDEN) sb[t] = b1[t];
    for (int i = t; i < BK * 9; i += 1024) tile2[i] = make_uint2(0u, 0u);
    __syncthreads();
    unsigned e0 = blockIdx.x * CAP;
    unsigned e1 = cursor[blockIdx.x];
    unsigned e = e0 + t;
    for (; e + 2048 < e1; e += 3072) {
        unsigned m0 = __builtin_nontemporal_load(&binnedM[e]);
        unsigned m1 = __builtin_nontemporal_load(&binnedM[e + 1024]);
        unsigned m2 = __builtin_nontemporal_load(&binnedM[e + 2048]);
        unsigned short w0 = __builtin_nontemporal_load(&binnedT[e]);
        unsigned short w1 = __builtin_nontemporal_load(&binnedT[e + 1024]);
        unsigned short w2 = __builtin_nontemporal_load(&binnedT[e + 2048]);
        unsigned s0 = m0 & 0x1FFFFu, d0 = m0 >> 17;
        unsigned s1 = m1 & 0x1FFFFu, d1 = m1 >> 17;
        unsigned s2 = m2 & 0x1FFFFu, d2 = m2 >> 17;
        float t0 = __uint_as_float((unsigned)w0 << 16);
        float t1 = __uint_as_float((unsigned)w1 << 16);
        float t2 = __uint_as_float((unsigned)w2 << 16);
        uint4 a0 = xb[s0 * 2], c0 = xb[s0 * 2 + 1];
        uint4 a1 = xb[s1 * 2], c1 = xb[s1 * 2 + 1];
        uint4 a2 = xb[s2 * 2], c2 = xb[s2 * 2 + 1];
        agg16c(tile + d0 * 18, a0, c0, t0);
        agg16c(tile + d1 * 18, a1, c1, t1);
        agg16c(tile + d2 * 18, a2, c2, t2);
    }
    for (; e < e1; e += 1024) {
        unsigned m0 = __builtin_nontemporal_load(&binnedM[e]);
        unsigned short w0 = __builtin_nontemporal_load(&binnedT[e]);
        unsigned s0 = m0 & 0x1FFFFu, d0 = m0 >> 17;
        float t0 = __uint_as_float((unsigned)w0 << 16);
        uint4 a0 = xb[s0 * 2], c0 = xb[s0 * 2 + 1];
        agg16c(tile + d0 * 18, a0, c0, t0);
    }
    __syncthreads();
    int node = blockIdx.x * BK + t;
    if (t < BK && node < N_NODES) {
        float a[IN_FEATS];
#pragma unroll
        for (int f = 0; f < IN_FEATS; ++f) a[f] = key2f(tile[t * 18 + f]);
        float o[HIDDEN];
#pragma unroll
        for (int j = 0; j < HIDDEN; ++j) {
            float sacc = sb[j];
#pragma unroll
            for (int f = 0; f < IN_FEATS; ++f) sacc += a[f] * sW[f * HIDDEN + j];
            o[j] = fmaxf(sacc, 0.f);
        }
        hb[node] = make_uint4(pack_bf16(o[0], o[1]), pack_bf16(o[2], o[3]),
                              pack_bf16(o[4], o[5]), pack_bf16(o[6], o[7]));
    }
}

// ---------- 8-feat compare-then-atomic (stride 10 u32) ----------
__device__ __forceinline__ void agg8c(unsigned* row, uint4 a, float tv) {
    const unsigned* pa = (const unsigned*)&a;
#pragma unroll
    for (int w = 0; w < 4; ++w) {
        unsigned u = pa[w];
        unsigned k0 = f2key(__uint_as_float(u << 16) * tv);
        unsigned k1 = f2key(__uint_as_float(u & 0xFFFF0000u) * tv);
        uint2 cur = *(const uint2*)(row + 2 * w);
        if (k0 > cur.x) atomicMax(row + 2 * w,     k0);
        if (k1 > cur.y) atomicMax(row + 2 * w + 1, k1);
    }
}

// ---------- fused layer 2: bf16 h gather + LDS max + GEMV 8->2 ----------
__global__ __launch_bounds__(1024, 8) void layer2(
    const unsigned* __restrict__ cursor, const unsigned* __restrict__ binnedM,
    const unsigned short* __restrict__ binnedT, const uint4* __restrict__ hb,
    const float* __restrict__ W2, const float* __restrict__ b2,
    float* __restrict__ out) {
    __shared__ uint2 tile2[BK * 5];       // stride 10 u32 per node row
    __shared__ float sW[HIDDEN * N_CLASSES];
    __shared__ float sb[N_CLASSES];
    unsigned* tile = (unsigned*)tile2;
    int t = threadIdx.x;
    if (t < HIDDEN * N_CLASSES) sW[t] = W2[t];
    if (t < N_CLASSES) sb[t] = b2[t];
    for (int i = t; i < BK * 5; i += 1024) tile2[i] = make_uint2(0u, 0u);
    __syncthreads();
    unsigned e0 = blockIdx.x * CAP;
    unsigned e1 = cursor[blockIdx.x];
    unsigned e = e0 + t;
    for (; e + 3072 < e1; e += 4096) {
        unsigned m0 = __builtin_nontemporal_load(&binnedM[e]);
        unsigned m1 = __builtin_nontemporal_load(&binnedM[e + 1024]);
        unsigned m2 = __builtin_nontemporal_load(&binnedM[e + 2048]);
        unsigned m3 = __builtin_nontemporal_load(&binnedM[e + 3072]);
        unsigned short w0 = __builtin_nontemporal_load(&binnedT[e]);
        unsigned short w1 = __builtin_nontemporal_load(&binnedT[e + 1024]);
        unsigned short w2 = __builtin_nontemporal_load(&binnedT[e + 2048]);
        unsigned short w3 = __builtin_nontemporal_load(&binnedT[e + 3072]);
        unsigned s0 = m0 & 0x1FFFFu, d0 = m0 >> 17;
        unsigned s1 = m1 & 0x1FFFFu, d1 = m1 >> 17;
        unsigned s2 = m2 & 0x1FFFFu, d2 = m2 >> 17;
        unsigned s3 = m3 & 0x1FFFFu, d3 = m3 >> 17;
        float t0 = __uint_as_float((unsigned)w0 << 16);
        float t1 = __uint_as_float((unsigned)w1 << 16);
        float t2 = __uint_as_float((unsigned)w2 << 16);
        float t3 = __uint_as_float((unsigned)w3 << 16);
        uint4 h0 = hb[s0], h1 = hb[s1], h2 = hb[s2], h3 = hb[s3];
        agg8c(tile + d0 * 10, h0, t0);
        agg8c(tile + d1 * 10, h1, t1);
        agg8c(tile + d2 * 10, h2, t2);
        agg8c(tile + d3 * 10, h3, t3);
    }
    for (; e < e1; e += 1024) {
        unsigned m0 = __builtin_nontemporal_load(&binnedM[e]);
        unsigned short w0 = __builtin_nontemporal_load(&binnedT[e]);
        unsigned s0 = m0 & 0x1FFFFu, d0 = m0 >> 17;
        float t0 = __uint_as_float((unsigned)w0 << 16);
        agg8c(tile + d0 * 10, hb[s0], t0);
    }
    __syncthreads();
    int node = blockIdx.x * BK + t;
    if (t < BK && node < N_NODES) {
        float a[HIDDEN];
#pragma unroll
        for (int f = 0; f < HIDDEN; ++f) a[f] = key2f(tile[t * 10 + f]);
        float o0 = sb[0], o1 = sb[1];
#pragma unroll
        for (int f = 0; f < HIDDEN; ++f) {
            o0 += a[f] * sW[f * N_CLASSES + 0];
            o1 += a[f] * sW[f * N_CLASSES + 1];
        }
        ((float2*)out)[node] = make_float2(o0, o1);
    }
}

// ---------- fallback: R0 global atomic scatter ----------
__global__ void fb_init_keys(unsigned* __restrict__ k1, unsigned* __restrict__ k2) {
    int i = blockIdx.x * blockDim.x + threadIdx.x;
    for (int idx = i; idx < N_NODES * IN_FEATS; idx += gridDim.x * blockDim.x) k1[idx] = 0u;
    for (int idx = i; idx < N_NODES * HIDDEN; idx += gridDim.x * blockDim.x) k2[idx] = 0u;
}
__global__ void fb_scatter1(const int* __restrict__ src, const int* __restrict__ dst,
                            const float* __restrict__ ts, const float* __restrict__ x,
                            unsigned* __restrict__ agg) {
    int e = blockIdx.x * blockDim.x + threadIdx.x;
    if (e >= N_EDGES) return;
    int s = src[e]; int d = dst[e]; float t = ts[e];
    const float4* xs = (const float4*)(x + (size_t)s * IN_FEATS);
    unsigned* a = agg + (size_t)d * IN_FEATS;
#pragma unroll
    for (int q = 0; q < 4; ++q) {
        float4 v = xs[q];
        atomicMax(a + q * 4 + 0, f2key(v.x * t));
        atomicMax(a + q * 4 + 1, f2key(v.y * t));
        atomicMax(a + q * 4 + 2, f2key(v.z * t));
        atomicMax(a + q * 4 + 3, f2key(v.w * t));
    }
}
__global__ void fb_node1(const unsigned* __restrict__ agg, const float* __restrict__ W1,
                         const float* __restrict__ b1, float* __restrict__ h) {
    int n = blockIdx.x * blockDim.x + threadIdx.x;
    if (n >= N_NODES) return;
    float a[IN_FEATS];
#pragma unroll
    for (int f = 0; f < IN_FEATS; ++f) a[f] = key2f(agg[(size_t)n * IN_FEATS + f]);
#pragma unroll
    for (int j = 0; j < HIDDEN; ++j) {
        float acc = b1[j];
#pragma unroll
        for (int f = 0; f < IN_FEATS; ++f) acc += a[f] * W1[f * HIDDEN + j];
        h[(size_t)n * HIDDEN + j] = acc > 0.f ? acc : 0.f;
    }
}
__global__ void fb_scatter2(const int* __restrict__ src, const int* __restrict__ dst,
                            const float* __restrict__ ts, const float* __restrict__ h,
                            unsigned* __restrict__ agg) {
    int e = blockIdx.x * blockDim.x + threadIdx.x;
    if (e >= N_EDGES) return;
    int s = src[e]; int d = dst[e]; float t = ts[e];
    const float4* hs = (const float4*)(h + (size_t)s * HIDDEN);
    unsigned* a = agg + (size_t)d * HIDDEN;
#pragma unroll
    for (int q = 0; q < 2; ++q) {
        float4 v = hs[q];
        atomicMax(a + q * 4 + 0, f2key(v.x * t));
        atomicMax(a + q * 4 + 1, f2key(v.y * t));
        atomicMax(a + q * 4 + 2, f2key(v.z * t));
        atomicMax(a + q * 4 + 3, f2key(v.w * t));
    }
}
__global__ void fb_node2(const unsigned* __restrict__ agg, const float* __restrict__ W2,
                         const float* __restrict__ b2, float* __restrict__ out) {
    int n = blockIdx.x * blockDim.x + threadIdx.x;
    if (n >= N_NODES) return;
    float a[HIDDEN];
#pragma unroll
    for (int f = 0; f < HIDDEN; ++f) a[f] = key2f(agg[(size_t)n * HIDDEN + f]);
#pragma unroll
    for (int j = 0; j < N_CLASSES; ++j) {
        float acc = b2[j];
#pragma unroll
        for (int f = 0; f < HIDDEN; ++f) acc += a[f] * W2[f * N_CLASSES + j];
        out[(size_t)n * N_CLASSES + j] = acc;
    }
}

// ---------- launch ----------
extern "C" void kernel_launch(void* const* d_in, const int* in_sizes, int n_in,
                              void* d_out, int out_size, void* d_ws, size_t ws_size,
                              hipStream_t stream) {
    const float* x  = (const float*)d_in[0];
    const int* src  = (const int*)d_in[1];
    const int* dst  = (const int*)d_in[2];
    const float* ts = (const float*)d_in[3];
    const float* W1 = (const float*)d_in[4];
    const float* b1 = (const float*)d_in[5];
    const float* W2 = (const float*)d_in[6];
    const float* b2 = (const float*)d_in[7];
    float* out = (float*)d_out;

    char* ws = (char*)d_ws;
    size_t off = 0;
    auto alloc = [&](size_t bytes) { char* p = ws + off; off += (bytes + 255) & ~(size_t)255; return p; };

    unsigned* cursor        = (unsigned*)alloc(NBK * 4);
    unsigned* binnedM       = (unsigned*)alloc((size_t)NBK * CAP * 4);  // 33.5 MB
    unsigned short* binnedT = (unsigned short*)alloc((size_t)NBK * CAP * 2); // 16.8 MB
    uint4*    hb            = (uint4*)alloc((size_t)N_NODES * 16);
    unsigned* xb            = (unsigned*)alloc((size_t)N_NODES * IN_FEATS * 2);
    size_t fast_need = off;

    int eblocks = (N_EDGES + EPB - 1) / EPB;

    if (fast_need <= ws_size) {
        init_cursor<<<1, NBK, 0, stream>>>(cursor);
        binfill<<<eblocks, 1024, 0, stream>>>(x, src, dst, ts, cursor, binnedM, binnedT, xb);
        layer1<<<NBK, 1024, 0, stream>>>(cursor, binnedM, binnedT, (const uint4*)xb, W1, b1, hb);
        layer2<<<NBK, 1024, 0, stream>>>(cursor, binnedM, binnedT, hb, W2, b2, out);
    } else {
        unsigned* k1 = (unsigned*)d_ws;
        float* hh    = (float*)(k1 + (size_t)N_NODES * IN_FEATS);
        unsigned* k2 = (unsigned*)(hh + (size_t)N_NODES * HIDDEN);
        int eb = (N_EDGES + 255) / 256;
        fb_init_keys<<<2048, 256, 0, stream>>>(k1, k2);
        fb_scatter1<<<eb, 256, 0, stream>>>(src, dst, ts, x, k1);
        fb_node1<<<(N_NODES + 255) / 256, 256, 0, stream>>>(k1, W1, b1, hh);
        fb_scatter2<<<eb, 256, 0, stream>>>(src, dst, ts, hh, k2);
        fb_node2<<<(N_NODES + 255) / 256, 256, 0, stream>>>(k2, W2, b2, out);
    }
}

// Round 14
// 167.256 us; speedup vs baseline: 1.0828x; 1.0828x over previous
//
#include <hip/hip_runtime.h>
#include <hip/hip_bf16.h>

#define N_NODES 100000
#define N_EDGES 6500000
#define IN_FEATS 16
#define HIDDEN 8
#define N_CLASSES 2
#define BK 196            // nodes per bucket
#define NBK 512           // buckets: 512*196 = 100352 >= 100000
#define EPB 8192          // edges per block in binfill
#define CAP 16384         // fixed slots per bucket (max true load ~13.3K)

// Monotone float -> uint key (order-preserving); 0 is below every real key.
__device__ __forceinline__ unsigned f2key(float f) {
    int i = __float_as_int(f);
    return (unsigned)(i ^ ((i >> 31) | 0x80000000));
}
__device__ __forceinline__ float key2f(unsigned u) {
    int i = (u & 0x80000000u) ? (int)(u ^ 0x80000000u) : (int)(~u);
    return __int_as_float(i);
}
__device__ __forceinline__ unsigned bf16_1(float f0) {
    unsigned u0 = __float_as_uint(f0);
    return (u0 + 0x7FFFu + ((u0 >> 16) & 1u)) >> 16;   // RNE
}
__device__ __forceinline__ unsigned pack_bf16(float f0, float f1) {
    return bf16_1(f0) | (bf16_1(f1) << 16);
}

// ---------- cursor init: cursor[b] = b*CAP ----------
__global__ void init_cursor(unsigned* __restrict__ cursor) {
    int t = threadIdx.x;
    if (t < NBK) cursor[t] = (unsigned)t * CAP;
}

// ---------- bin-fill + fused x->bf16 convert (R9 proven shape) ----------
__global__ __launch_bounds__(1024, 8) void binfill(
    const float* __restrict__ x, const int* __restrict__ src,
    const int* __restrict__ dst, const float* __restrict__ ts,
    unsigned* __restrict__ cursor, uint2* __restrict__ binned,
    uint2* __restrict__ xb2) {
    __shared__ uint2 stage[EPB];          // 64 KB, bucket-sorted records
    __shared__ unsigned lcnt[NBK];
    __shared__ unsigned lstart[NBK + 1];
    __shared__ unsigned shiftv[NBK];      // global_base - local_start
    __shared__ unsigned chunkb[EPB / 64]; // bucket of each 64-record chunk
    __shared__ unsigned waveTot[8], waveBase[8];
    int t = threadIdx.x;
    if (t < NBK) lcnt[t] = 0u;
    // phase 0: x -> bf16 table, float4-vectorized (complete before layer1)
    {
        const float4* x4 = (const float4*)x;
        int total4 = N_NODES * IN_FEATS / 4;
        for (int i = blockIdx.x * 1024 + t; i < total4; i += gridDim.x * 1024) {
            float4 v = x4[i];
            xb2[i] = make_uint2(pack_bf16(v.x, v.y), pack_bf16(v.z, v.w));
        }
    }
    __syncthreads();
    int base = blockIdx.x * EPB;
    // phase 1a: preload 8 dst values (independent loads in flight)
    unsigned dvals[8];
#pragma unroll
    for (int k = 0; k < 8; ++k) {
        int e = base + k * 1024 + t;
        dvals[k] = (e < N_EDGES) ? (unsigned)__builtin_nontemporal_load(&dst[e]) : 0xFFFFFFFFu;
    }
    // phase 1b: count + capture slot
    unsigned pk[8];                       // drow<<22 | b<<13 | slot
#pragma unroll
    for (int k = 0; k < 8; ++k) {
        pk[k] = 0xFFFFFFFFu;
        if (dvals[k] != 0xFFFFFFFFu) {
            unsigned d = dvals[k];
            unsigned b = d / BK;
            unsigned slot = atomicAdd(&lcnt[b], 1u);
            pk[k] = ((d - b * BK) << 22) | (b << 13) | slot;
        }
    }
    __syncthreads();
    // phase 2: wave-shfl scan over lcnt -> lstart; reserve global runs
    unsigned c = (t < NBK) ? lcnt[t] : 0u;
    unsigned inc = c;
    int lane = t & 63;
#pragma unroll
    for (int d = 1; d < 64; d <<= 1) {
        unsigned v = __shfl_up(inc, d, 64);
        if (lane >= d) inc += v;
    }
    if (t < NBK && lane == 63) waveTot[t >> 6] = inc;
    __syncthreads();
    if (t == 0) {
        unsigned acc = 0;
#pragma unroll
        for (int w = 0; w < 8; ++w) { waveBase[w] = acc; acc += waveTot[w]; }
    }
    __syncthreads();
    if (t < NBK) {
        unsigned excl = waveBase[t >> 6] + inc - c;
        lstart[t] = excl;
        unsigned gb = atomicAdd(&cursor[t], c);   // block-private run in [b*CAP ...)
        shiftv[t] = gb - excl;
        if (t == NBK - 1) lstart[NBK] = excl + c;
    }
    __syncthreads();
    // phase 3: reload src/ts (L2-hot), scatter into stage (bucket-sorted)
#pragma unroll
    for (int k = 0; k < 8; ++k) {
        if (pk[k] != 0xFFFFFFFFu) {
            int e = base + k * 1024 + t;
            unsigned b = (pk[k] >> 13) & 511u;
            unsigned pos = lstart[b] + (pk[k] & 8191u);
            unsigned sv = (unsigned)__builtin_nontemporal_load(&src[e]);
            float tv = __builtin_nontemporal_load(&ts[e]);
            stage[pos] = make_uint2(sv | ((pk[k] >> 22) << 17), __float_as_uint(tv));
        }
    }
    __syncthreads();
    unsigned total = lstart[NBK];
    // phase 4a: chunk->bucket table (one binary search per 64 records)
    if (t < EPB / 64) {
        unsigned i = (unsigned)t * 64u;
        if (i < total) {
            unsigned lo = 0, hi = NBK - 1;
            while (lo < hi) {
                unsigned mid = (lo + hi + 1) >> 1;
                if (lstart[mid] <= i) lo = mid; else hi = mid - 1;
            }
            chunkb[t] = lo;
        }
    }
    __syncthreads();
    // phase 4b: dense copy-out; chunk-seeded walk, coalesced nt stores
#pragma unroll
    for (int j = 0; j < 8; ++j) {
        unsigned i = (unsigned)t + j * 1024u;
        if (i < total) {
            unsigned lo = chunkb[i >> 6];
            while (i >= lstart[lo + 1]) ++lo;
            uint2 v = stage[i];
            __builtin_nontemporal_store(((unsigned long long)v.y << 32) | v.x,
                                        (unsigned long long*)&binned[i + shiftv[lo]]);
        }
    }
}

// ---------- 16-feat compare-then-atomic from packed-bf16 pair of uint4 ----------
__device__ __forceinline__ void agg16c(unsigned* row, uint4 a, uint4 b, float tv) {
    const unsigned* pa = (const unsigned*)&a;
    const unsigned* pb = (const unsigned*)&b;
#pragma unroll
    for (int w = 0; w < 8; ++w) {
        unsigned u = (w < 4) ? pa[w] : pb[w - 4];
        unsigned k0 = f2key(__uint_as_float(u << 16) * tv);
        unsigned k1 = f2key(__uint_as_float(u & 0xFFFF0000u) * tv);
        uint2 cur = *(const uint2*)(row + 2 * w);
        if (k0 > cur.x) atomicMax(row + 2 * w,     k0);
        if (k1 > cur.y) atomicMax(row + 2 * w + 1, k1);
    }
}

// ---------- fused layer 1: bf16 gather + LDS max + GEMV 16->8 + relu ----------
__global__ __launch_bounds__(1024, 8) void layer1(
    const unsigned* __restrict__ cursor, const uint2* __restrict__ binned,
    const uint4* __restrict__ xb, const float* __restrict__ W1,
    const float* __restrict__ b1, uint4* __restrict__ hb) {
    __shared__ uint2 tile2[BK * 9];       // stride 18 u32 per node row
    __shared__ float sW[IN_FEATS * HIDDEN];
    __shared__ float sb[HIDDEN];
    unsigned* tile = (unsigned*)tile2;
    int t = threadIdx.x;
    if (t < IN_FEATS * HIDDEN) sW[t] = W1[t];
    if (t < HIDDEN) sb[t] = b1[t];
    for (int i = t; i < BK * 9; i += 1024) tile2[i] = make_uint2(0u, 0u);
    __syncthreads();
    unsigned e0 = blockIdx.x * CAP;
    unsigned e1 = cursor[blockIdx.x];
    unsigned e = e0 + t;
    for (; e + 2048 < e1; e += 3072) {
        unsigned long long r0 = __builtin_nontemporal_load((const unsigned long long*)&binned[e]);
        unsigned long long r1 = __builtin_nontemporal_load((const unsigned long long*)&binned[e + 1024]);
        unsigned long long r2 = __builtin_nontemporal_load((const unsigned long long*)&binned[e + 2048]);
        unsigned s0 = (unsigned)r0 & 0x1FFFFu, d0 = ((unsigned)r0) >> 17;
        unsigned s1 = (unsigned)r1 & 0x1FFFFu, d1 = ((unsigned)r1) >> 17;
        unsigned s2 = (unsigned)r2 & 0x1FFFFu, d2 = ((unsigned)r2) >> 17;
        float t0 = __uint_as_float((unsigned)(r0 >> 32));
        float t1 = __uint_as_float((unsigned)(r1 >> 32));
        float t2 = __uint_as_float((unsigned)(r2 >> 32));
        uint4 a0 = xb[s0 * 2], c0 = xb[s0 * 2 + 1];
        uint4 a1 = xb[s1 * 2], c1 = xb[s1 * 2 + 1];
        uint4 a2 = xb[s2 * 2], c2 = xb[s2 * 2 + 1];
        agg16c(tile + d0 * 18, a0, c0, t0);
        agg16c(tile + d1 * 18, a1, c1, t1);
        agg16c(tile + d2 * 18, a2, c2, t2);
    }
    for (; e < e1; e += 1024) {
        unsigned long long r0 = __builtin_nontemporal_load((const unsigned long long*)&binned[e]);
        unsigned s0 = (unsigned)r0 & 0x1FFFFu, d0 = ((unsigned)r0) >> 17;
        float t0 = __uint_as_float((unsigned)(r0 >> 32));
        uint4 a0 = xb[s0 * 2], c0 = xb[s0 * 2 + 1];
        agg16c(tile + d0 * 18, a0, c0, t0);
    }
    __syncthreads();
    int node = blockIdx.x * BK + t;
    if (t < BK && node < N_NODES) {
        float a[IN_FEATS];
#pragma unroll
        for (int f = 0; f < IN_FEATS; ++f) a[f] = key2f(tile[t * 18 + f]);
        float o[HIDDEN];
#pragma unroll
        for (int j = 0; j < HIDDEN; ++j) {
            float sacc = sb[j];
#pragma unroll
            for (int f = 0; f < IN_FEATS; ++f) sacc += a[f] * sW[f * HIDDEN + j];
            o[j] = fmaxf(sacc, 0.f);
        }
        hb[node] = make_uint4(pack_bf16(o[0], o[1]), pack_bf16(o[2], o[3]),
                              pack_bf16(o[4], o[5]), pack_bf16(o[6], o[7]));
    }
}

// ---------- 8-feat compare-then-atomic (stride 10 u32) ----------
__device__ __forceinline__ void agg8c(unsigned* row, uint4 a, float tv) {
    const unsigned* pa = (const unsigned*)&a;
#pragma unroll
    for (int w = 0; w < 4; ++w) {
        unsigned u = pa[w];
        unsigned k0 = f2key(__uint_as_float(u << 16) * tv);
        unsigned k1 = f2key(__uint_as_float(u & 0xFFFF0000u) * tv);
        uint2 cur = *(const uint2*)(row + 2 * w);
        if (k0 > cur.x) atomicMax(row + 2 * w,     k0);
        if (k1 > cur.y) atomicMax(row + 2 * w + 1, k1);
    }
}

// ---------- fused layer 2: bf16 h gather + LDS max + GEMV 8->2 ----------
__global__ __launch_bounds__(1024, 8) void layer2(
    const unsigned* __restrict__ cursor, const uint2* __restrict__ binned,
    const uint4* __restrict__ hb, const float* __restrict__ W2,
    const float* __restrict__ b2, float* __restrict__ out) {
    __shared__ uint2 tile2[BK * 5];       // stride 10 u32 per node row
    __shared__ float sW[HIDDEN * N_CLASSES];
    __shared__ float sb[N_CLASSES];
    unsigned* tile = (unsigned*)tile2;
    int t = threadIdx.x;
    if (t < HIDDEN * N_CLASSES) sW[t] = W2[t];
    if (t < N_CLASSES) sb[t] = b2[t];
    for (int i = t; i < BK * 5; i += 1024) tile2[i] = make_uint2(0u, 0u);
    __syncthreads();
    unsigned e0 = blockIdx.x * CAP;
    unsigned e1 = cursor[blockIdx.x];
    unsigned e = e0 + t;
    for (; e + 3072 < e1; e += 4096) {
        unsigned long long r0 = __builtin_nontemporal_load((const unsigned long long*)&binned[e]);
        unsigned long long r1 = __builtin_nontemporal_load((const unsigned long long*)&binned[e + 1024]);
        unsigned long long r2 = __builtin_nontemporal_load((const unsigned long long*)&binned[e + 2048]);
        unsigned long long r3 = __builtin_nontemporal_load((const unsigned long long*)&binned[e + 3072]);
        unsigned s0 = (unsigned)r0 & 0x1FFFFu, d0 = ((unsigned)r0) >> 17;
        unsigned s1 = (unsigned)r1 & 0x1FFFFu, d1 = ((unsigned)r1) >> 17;
        unsigned s2 = (unsigned)r2 & 0x1FFFFu, d2 = ((unsigned)r2) >> 17;
        unsigned s3 = (unsigned)r3 & 0x1FFFFu, d3 = ((unsigned)r3) >> 17;
        float t0 = __uint_as_float((unsigned)(r0 >> 32));
        float t1 = __uint_as_float((unsigned)(r1 >> 32));
        float t2 = __uint_as_float((unsigned)(r2 >> 32));
        float t3 = __uint_as_float((unsigned)(r3 >> 32));
        uint4 h0 = hb[s0], h1 = hb[s1], h2 = hb[s2], h3 = hb[s3];
        agg8c(tile + d0 * 10, h0, t0);
        agg8c(tile + d1 * 10, h1, t1);
        agg8c(tile + d2 * 10, h2, t2);
        agg8c(tile + d3 * 10, h3, t3);
    }
    for (; e < e1; e += 1024) {
        unsigned long long r0 = __builtin_nontemporal_load((const unsigned long long*)&binned[e]);
        unsigned s0 = (unsigned)r0 & 0x1FFFFu, d0 = ((unsigned)r0) >> 17;
        float t0 = __uint_as_float((unsigned)(r0 >> 32));
        agg8c(tile + d0 * 10, hb[s0], t0);
    }
    __syncthreads();
    int node = blockIdx.x * BK + t;
    if (t < BK && node < N_NODES) {
        float a[HIDDEN];
#pragma unroll
        for (int f = 0; f < HIDDEN; ++f) a[f] = key2f(tile[t * 10 + f]);
        float o0 = sb[0], o1 = sb[1];
#pragma unroll
        for (int f = 0; f < HIDDEN; ++f) {
            o0 += a[f] * sW[f * N_CLASSES + 0];
            o1 += a[f] * sW[f * N_CLASSES + 1];
        }
        ((float2*)out)[node] = make_float2(o0, o1);
    }
}

// ---------- fallback: R0 global atomic scatter ----------
__global__ void fb_init_keys(unsigned* __restrict__ k1, unsigned* __restrict__ k2) {
    int i = blockIdx.x * blockDim.x + threadIdx.x;
    for (int idx = i; idx < N_NODES * IN_FEATS; idx += gridDim.x * blockDim.x) k1[idx] = 0u;
    for (int idx = i; idx < N_NODES * HIDDEN; idx += gridDim.x * blockDim.x) k2[idx] = 0u;
}
__global__ void fb_scatter1(const int* __restrict__ src, const int* __restrict__ dst,
                            const float* __restrict__ ts, const float* __restrict__ x,
                            unsigned* __restrict__ agg) {
    int e = blockIdx.x * blockDim.x + threadIdx.x;
    if (e >= N_EDGES) return;
    int s = src[e]; int d = dst[e]; float t = ts[e];
    const float4* xs = (const float4*)(x + (size_t)s * IN_FEATS);
    unsigned* a = agg + (size_t)d * IN_FEATS;
#pragma unroll
    for (int q = 0; q < 4; ++q) {
        float4 v = xs[q];
        atomicMax(a + q * 4 + 0, f2key(v.x * t));
        atomicMax(a + q * 4 + 1, f2key(v.y * t));
        atomicMax(a + q * 4 + 2, f2key(v.z * t));
        atomicMax(a + q * 4 + 3, f2key(v.w * t));
    }
}
__global__ void fb_node1(const unsigned* __restrict__ agg, const float* __restrict__ W1,
                         const float* __restrict__ b1, float* __restrict__ h) {
    int n = blockIdx.x * blockDim.x + threadIdx.x;
    if (n >= N_NODES) return;
    float a[IN_FEATS];
#pragma unroll
    for (int f = 0; f < IN_FEATS; ++f) a[f] = key2f(agg[(size_t)n * IN_FEATS + f]);
#pragma unroll
    for (int j = 0; j < HIDDEN; ++j) {
        float acc = b1[j];
#pragma unroll
        for (int f = 0; f < IN_FEATS; ++f) acc += a[f] * W1[f * HIDDEN + j];
        h[(size_t)n * HIDDEN + j] = acc > 0.f ? acc : 0.f;
    }
}
__global__ void fb_scatter2(const int* __restrict__ src, const int* __restrict__ dst,
                            const float* __restrict__ ts, const float* __restrict__ h,
                            unsigned* __restrict__ agg) {
    int e = blockIdx.x * blockDim.x + threadIdx.x;
    if (e >= N_EDGES) return;
    int s = src[e]; int d = dst[e]; float t = ts[e];
    const float4* hs = (const float4*)(h + (size_t)s * HIDDEN);
    unsigned* a = agg + (size_t)d * HIDDEN;
#pragma unroll
    for (int q = 0; q < 2; ++q) {
        float4 v = hs[q];
        atomicMax(a + q * 4 + 0, f2key(v.x * t));
        atomicMax(a + q * 4 + 1, f2key(v.y * t));
        atomicMax(a + q * 4 + 2, f2key(v.z * t));
        atomicMax(a + q * 4 + 3, f2key(v.w * t));
    }
}
__global__ void fb_node2(const unsigned* __restrict__ agg, const float* __restrict__ W2,
                         const float* __restrict__ b2, float* __restrict__ out) {
    int n = blockIdx.x * blockDim.x + threadIdx.x;
    if (n >= N_NODES) return;
    float a[HIDDEN];
#pragma unroll
    for (int f = 0; f < HIDDEN; ++f) a[f] = key2f(agg[(size_t)n * HIDDEN + f]);
#pragma unroll
    for (int j = 0; j < N_CLASSES; ++j) {
        float acc = b2[j];
#pragma unroll
        for (int f = 0; f < HIDDEN; ++f) acc += a[f] * W2[f * N_CLASSES + j];
        out[(size_t)n * N_CLASSES + j] = acc;
    }
}

// ---------- launch ----------
extern "C" void kernel_launch(void* const* d_in, const int* in_sizes, int n_in,
                              void* d_out, int out_size, void* d_ws, size_t ws_size,
                              hipStream_t stream) {
    const float* x  = (const float*)d_in[0];
    const int* src  = (const int*)d_in[1];
    const int* dst  = (const int*)d_in[2];
    const float* ts = (const float*)d_in[3];
    const float* W1 = (const float*)d_in[4];
    const float* b1 = (const float*)d_in[5];
    const float* W2 = (const float*)d_in[6];
    const float* b2 = (const float*)d_in[7];
    float* out = (float*)d_out;

    char* ws = (char*)d_ws;
    size_t off = 0;
    auto alloc = [&](size_t bytes) { char* p = ws + off; off += (bytes + 255) & ~(size_t)255; return p; };

    unsigned* cursor = (unsigned*)alloc(NBK * 4);
    uint2*    binned = (uint2*)alloc((size_t)NBK * CAP * 8);   // 67 MB fixed-cap runs
    uint4*    hb     = (uint4*)alloc((size_t)N_NODES * 16);
    unsigned* xb     = (unsigned*)alloc((size_t)N_NODES * IN_FEATS * 2);
    size_t fast_need = off;

    int eblocks = (N_EDGES + EPB - 1) / EPB;

    if (fast_need <= ws_size) {
        init_cursor<<<1, NBK, 0, stream>>>(cursor);
        binfill<<<eblocks, 1024, 0, stream>>>(x, src, dst, ts, cursor, binned, (uint2*)xb);
        layer1<<<NBK, 1024, 0, stream>>>(cursor, binned, (const uint4*)xb, W1, b1, hb);
        layer2<<<NBK, 1024, 0, stream>>>(cursor, binned, hb, W2, b2, out);
    } else {
        unsigned* k1 = (unsigned*)d_ws;
        float* hh    = (float*)(k1 + (size_t)N_NODES * IN_FEATS);
        unsigned* k2 = (unsigned*)(hh + (size_t)N_NODES * HIDDEN);
        int eb = (N_EDGES + 255) / 256;
        fb_init_keys<<<2048, 256, 0, stream>>>(k1, k2);
        fb_scatter1<<<eb, 256, 0, stream>>>(src, dst, ts, x, k1);
        fb_node1<<<(N_NODES + 255) / 256, 256, 0, stream>>>(k1, W1, b1, hh);
        fb_scatter2<<<eb, 256, 0, stream>>>(src, dst, ts, hh, k2);
        fb_node2<<<(N_NODES + 255) / 256, 256, 0, stream>>>(k2, W2, b2, out);
    }
}